// Round 7
// baseline (238.952 us; speedup 1.0000x reference)
//
#include <hip/hip_runtime.h>
#include <math.h>
#include <stdint.h>

typedef __bf16 bf16_t;
typedef __attribute__((ext_vector_type(2))) __bf16 bf16x2;
typedef __attribute__((ext_vector_type(8))) __bf16 bf16x8;
typedef __attribute__((ext_vector_type(4))) float f32x4;
typedef __attribute__((ext_vector_type(16))) float f32x16;
typedef __attribute__((address_space(1))) unsigned int gu32;
typedef __attribute__((address_space(3))) unsigned int lu32;

#define MFMA16(a, b, c) __builtin_amdgcn_mfma_f32_16x16x32_bf16((a), (b), (c), 0, 0, 0)
#define MFMA32(a, b, c) __builtin_amdgcn_mfma_f32_32x32x16_bf16((a), (b), (c), 0, 0, 0)

// async global->LDS, 16 B per lane (wave-uniform base, lane i at base+i*16).
__device__ __forceinline__ void gll16(const void* g, void* l) {
    __builtin_amdgcn_global_load_lds((const gu32*)(uintptr_t)g,
                                     (lu32*)(uintptr_t)l, 16, 0, 0);
}

// fragment load from 8-B-aligned (stride-68) LDS rows: two ds_read_b64.
__device__ __forceinline__ bf16x8 ld_frag68(const bf16_t* p) {
    union { bf16x8 v; uint2 u[2]; } r;
    r.u[0] = *(const uint2*)p;
    r.u[1] = *(const uint2*)(p + 4);
    return r.v;
}

// ---------------------------------------------------------------------------
// convert 7 fp32 tensors -> one contiguous bf16 region in ws.
// ---------------------------------------------------------------------------
__global__ __launch_bounds__(256) void convert_all(
    const float* __restrict__ Q, const float* __restrict__ K, const float* __restrict__ V,
    const float* __restrict__ Wq, const float* __restrict__ Wk, const float* __restrict__ Wv,
    const float* __restrict__ Wo, bf16_t* __restrict__ dst) {
    size_t e0 = (size_t)blockIdx.x * 2048;
    const float* src; size_t off;
    if (e0 < 4194304)       { src = Q;  off = e0; }
    else if (e0 < 8388608)  { src = K;  off = e0 - 4194304; }
    else if (e0 < 12582912) { src = V;  off = e0 - 8388608; }
    else if (e0 < 13631488) { src = Wq; off = e0 - 12582912; }
    else if (e0 < 14680064) { src = Wk; off = e0 - 13631488; }
    else if (e0 < 15728640) { src = Wv; off = e0 - 14680064; }
    else                    { src = Wo; off = e0 - 15728640; }
#pragma unroll
    for (int p = 0; p < 2; ++p) {
        int t = p * 1024 + threadIdx.x * 4;
        float4 v = *(const float4*)(src + off + t);
        union { ushort4 u; bf16_t h[4]; } pk;
        pk.h[0] = (bf16_t)v.x; pk.h[1] = (bf16_t)v.y;
        pk.h[2] = (bf16_t)v.z; pk.h[3] = (bf16_t)v.w;
        *(ushort4*)(dst + e0 + t) = pk.u;
    }
}

// ---------------------------------------------------------------------------
// Fused QKV NT-GEMM, 2-wave wide-tile variant (attn8's reuse mechanism):
//   128-thread blocks, 2 waves; wave tile 64(M)x128(N): per K-tile each wave
//   does 24 ds_read_b128 -> 64 MFMA (ratio 2.67 vs 2.0) and 2x the MFMA per
//   barrier-pair -> barrier/stage stall amortized 2x.  Single 32 KiB buffer
//   keeps 3 blocks/CU resident (grid 768).  T2 XOR swizzle retained:
//   LDS 16B-slot s of row r holds GLOBAL slot s^(r&7); stage linear gll16
//   dest + inverse-swizzled source col; read slot = ((ks>>3)+quad)^(row&7).
// grid (32, 8, 3): x = M-tile (8 N-blocks sharing A land on one XCD).
// z=0: qo scaled by 0.125*log2(e).  z=1: ko natural order.
// z=2: vT[b][h][d][sigma(l)], sigma swaps key-index bits 2<->3.
// ---------------------------------------------------------------------------
__global__ __launch_bounds__(128) void qkv_gemm(
    const bf16_t* __restrict__ Qb, const bf16_t* __restrict__ Kb, const bf16_t* __restrict__ Vb,
    const bf16_t* __restrict__ Wqb, const bf16_t* __restrict__ Wkb, const bf16_t* __restrict__ Wvb,
    const float* __restrict__ bq, const float* __restrict__ bk, const float* __restrict__ bv,
    bf16_t* __restrict__ qo, bf16_t* __restrict__ ko, bf16_t* __restrict__ vT) {
    constexpr int Kdim = 1024, N = 1024;
    __shared__ __attribute__((aligned(16))) bf16_t smem[2 * 128 * 64];  // 32 KiB
    bf16_t* As = smem;
    bf16_t* Bs = smem + 8192;

    const int tid = threadIdx.x, wave = tid >> 6, lane = tid & 63;
    const int z = blockIdx.z;
    const bf16_t* A = (z == 0) ? Qb : (z == 1) ? Kb : Vb;
    const bf16_t* W = (z == 0) ? Wqb : (z == 1) ? Wkb : Wvb;
    const float* bias = (z == 0) ? bq : (z == 1) ? bk : bv;
    const int bm = blockIdx.x * 128, bn = blockIdx.y * 128;
    const int l16 = lane & 15, quad = lane >> 4;
    const int wm = wave * 64;                         // wave M-offset (N: full 128)
    const int grow = lane >> 3;                       // 0..7 == row&7 in chunk
    const int gcol = (((lane & 7) ^ grow)) * 8;       // inverse-swizzled source
    const int rsw = l16 & 7;                          // read-side row swizzle

    f32x4 acc[4][8] = {};

    for (int k0 = 0; k0 < Kdim; k0 += 64) {
        // stage: 16 chunks of 8 rows x 64 cols; wave w covers chunks w*8..w*8+7
#pragma unroll
        for (int j = 0; j < 8; ++j) {
            int chunk = wave * 8 + j;
            int row = chunk * 8 + grow;
            gll16(A + (size_t)(bm + row) * Kdim + k0 + gcol, As + chunk * 512);
            gll16(W + (size_t)(bn + row) * Kdim + k0 + gcol, Bs + chunk * 512);
        }
        __syncthreads();
#pragma unroll
        for (int ks = 0; ks < 64; ks += 32) {
            const int so = (((ks >> 3) + quad) ^ rsw) * 8;
            bf16x8 af[4], bf[8];
#pragma unroll
            for (int i = 0; i < 4; ++i)
                af[i] = *(const bf16x8*)&As[(wm + i * 16 + l16) * 64 + so];
#pragma unroll
            for (int j = 0; j < 8; ++j)
                bf[j] = *(const bf16x8*)&Bs[(j * 16 + l16) * 64 + so];
#pragma unroll
            for (int i = 0; i < 4; ++i)
#pragma unroll
                for (int j = 0; j < 8; ++j)
                    acc[i][j] = MFMA16(af[i], bf[j], acc[i][j]);
        }
        __syncthreads();
    }

    if (z < 2) {
        bf16_t* outp = (z == 0) ? qo : ko;
        const float sc = (z == 0) ? 0.18033688011112042f : 1.0f;
        constexpr int RST = 132;  // repack row stride (66 dw: 2-way max on wr)
#pragma unroll
        for (int p = 0; p < 2; ++p) {  // row halves [64p, 64p+64) == wave p
            __syncthreads();
            if (wave == p) {
#pragma unroll
                for (int mi = 0; mi < 4; ++mi)
#pragma unroll
                    for (int nj = 0; nj < 8; ++nj) {
                        int col = nj * 16 + l16;
                        float bv_ = bias[bn + col];
#pragma unroll
                        for (int r = 0; r < 4; ++r) {
                            int rp = mi * 16 + quad * 4 + r;
                            smem[rp * RST + col] = (bf16_t)((acc[mi][nj][r] + bv_) * sc);
                        }
                    }
            }
            __syncthreads();
            // cooperative coalesced store: 64 rows x 128 cols, 128 threads
            int rp = tid >> 1;
            int cb2 = (tid & 1) * 64;
            int row = bm + p * 64 + rp;
#pragma unroll
            for (int j = 0; j < 8; ++j) {
                uint2 lo = *(const uint2*)&smem[rp * RST + cb2 + j * 8];
                uint2 hi = *(const uint2*)&smem[rp * RST + cb2 + j * 8 + 4];
                *(uint4*)&outp[(size_t)row * N + bn + cb2 + j * 8] =
                    make_uint4(lo.x, lo.y, hi.x, hi.y);
            }
        }
    } else {
#pragma unroll
        for (int mi = 0; mi < 4; ++mi)
#pragma unroll
            for (int nj = 0; nj < 8; ++nj) {
                int col = bn + nj * 16 + l16;
                int h = col >> 6, d = col & 63;
                float bv_ = bias[col];
                int row0 = bm + wm + mi * 16 + quad * 4;
                int bb = row0 >> 11, l = row0 & 2047;
                // sigma: swap key-index bits 2<->3 (4-aligned blocks preserved)
                int lb = (l & ~12) | ((l & 4) << 1) | ((l & 8) >> 1);
                union { ushort4 u; bf16_t h4[4]; } pk;
#pragma unroll
                for (int r = 0; r < 4; ++r) pk.h4[r] = (bf16_t)(acc[mi][nj][r] + bv_);
                *(ushort4*)&vT[(((size_t)bb * 16 + h) * 64 + d) * 2048 + lb] = pk.u;
            }
    }
}

// ---------------------------------------------------------------------------
// Out-projection GEMM with FUSED softmax-normalize (absorbs old `combine`):
//   A = (Op0 + Op1) * (1/(lp0+lp1)) computed in registers during staging
//   (reg-staged A replicating gll16's exact LDS layout; W stays gll16).
//   dbuf + T2 swizzle. grid (64, 8). k0 window == one head block (h=k0>>6),
//   so the lp index is per-row uniform within a staging chunk.
// ---------------------------------------------------------------------------
__global__ __launch_bounds__(256) void out_gemm(const bf16_t* __restrict__ Op,
                                                const float* __restrict__ lpp,
                                                const bf16_t* __restrict__ W,
                                                const float* __restrict__ bias,
                                                float* __restrict__ out) {
    constexpr int Kdim = 1024, N = 1024;
    // buf b at smem + b*12288: A 4096 elems (64x64), B 8192 elems (128x64)
    __shared__ __attribute__((aligned(16))) bf16_t smem[2 * 12288];  // 48 KiB
    const int tid = threadIdx.x, wave = tid >> 6, lane = tid & 63;
    const int bm = blockIdx.x * 64, bn = blockIdx.y * 128;
    const int l16 = lane & 15, quad = lane >> 4;
    const int wm = (wave >> 1) * 32, wn = (wave & 1) * 64;
    const int grow = lane >> 3;
    const int gcol = (((lane & 7) ^ grow)) * 8;
    const int rsw = l16 & 7;
    f32x4 acc[2][4] = {};

    // per-lane A rows for the wave's two 8-row chunks
    const int arow0 = bm + (wave * 2 + 0) * 8 + grow;
    const int arow1 = bm + (wave * 2 + 1) * 8 + grow;

    uint4 a0p, a0q, a1p, a1q;   // Op0/Op1 16B chunks for the two rows
    float ivn0, ivn1;           // 1/(lp0+lp1) per row (h = k0>>6 uniform)

    auto loadA = [&](int k0) {
        const int h = k0 >> 6;
        a0p = *(const uint4*)(Op + (size_t)arow0 * Kdim + k0 + gcol);
        a0q = *(const uint4*)(Op + 4194304 + (size_t)arow0 * Kdim + k0 + gcol);
        a1p = *(const uint4*)(Op + (size_t)arow1 * Kdim + k0 + gcol);
        a1q = *(const uint4*)(Op + 4194304 + (size_t)arow1 * Kdim + k0 + gcol);
        const int li0 = ((arow0 >> 11) * 16 + h) * 2048 + (arow0 & 2047);
        const int li1 = ((arow1 >> 11) * 16 + h) * 2048 + (arow1 & 2047);
        ivn0 = 1.f / (lpp[li0] + lpp[65536 + li0]);
        ivn1 = 1.f / (lpp[li1] + lpp[65536 + li1]);
    };
    auto writeA = [&](bf16_t* As) {
        union { uint4 u; bf16_t h8[8]; } x, y, w0, w1;
        x.u = a0p; y.u = a0q;
#pragma unroll
        for (int i = 0; i < 8; ++i)
            w0.h8[i] = (bf16_t)(((float)x.h8[i] + (float)y.h8[i]) * ivn0);
        x.u = a1p; y.u = a1q;
#pragma unroll
        for (int i = 0; i < 8; ++i)
            w1.h8[i] = (bf16_t)(((float)x.h8[i] + (float)y.h8[i]) * ivn1);
        *(uint4*)&As[(wave * 2 + 0) * 512 + lane * 8] = w0.u;
        *(uint4*)&As[(wave * 2 + 1) * 512 + lane * 8] = w1.u;
    };
    auto stageW = [&](int k0, bf16_t* Bs) {
#pragma unroll
        for (int j = 0; j < 4; ++j) {
            int chunk = wave * 4 + j;
            int row = chunk * 8 + grow;
            gll16(W + (size_t)(bn + row) * Kdim + k0 + gcol, Bs + chunk * 512);
        }
    };
    auto compute = [&](const bf16_t* As, const bf16_t* Bs) {
#pragma unroll
        for (int ks = 0; ks < 64; ks += 32) {
            const int so0 = (((ks >> 3) + quad) ^ rsw) * 8;
            bf16x8 af[2], bf[4];
#pragma unroll
            for (int i = 0; i < 2; ++i)
                af[i] = *(const bf16x8*)&As[(wm + i * 16 + l16) * 64 + so0];
#pragma unroll
            for (int i = 0; i < 4; ++i)
                bf[i] = *(const bf16x8*)&Bs[(wn + i * 16 + l16) * 64 + so0];
#pragma unroll
            for (int i = 0; i < 2; ++i)
#pragma unroll
                for (int j = 0; j < 4; ++j)
                    acc[i][j] = MFMA16(af[i], bf[j], acc[i][j]);
        }
    };

    // prologue: tile 0 -> buf0
    loadA(0);
    stageW(0, smem + 4096);
    writeA(smem);            // compiler waits vmcnt for a-regs only
    __syncthreads();         // drains gll16 (vmcnt 0) + ds writes, barrier
    int cur = 0;
    for (int t = 0; t < 15; ++t) {
        bf16_t* nb = smem + (cur ^ 1) * 12288;
        loadA((t + 1) * 64);           // A regs for next tile (in flight)
        stageW((t + 1) * 64, nb + 4096);  // W gll16 for next tile (in flight)
        bf16_t* cb = smem + cur * 12288;
        compute(cb, cb + 4096);        // MFMA hides both
        writeA(nb);                    // waits only the a-regs, not gll16
        asm volatile("s_waitcnt vmcnt(0)" ::: "memory");
        __syncthreads();
        cur ^= 1;
    }
    {
        bf16_t* cb = smem + cur * 12288;
        compute(cb, cb + 4096);
    }

#pragma unroll
    for (int mi = 0; mi < 2; ++mi)
#pragma unroll
        for (int nj = 0; nj < 4; ++nj) {
            int col = bn + wn + nj * 16 + l16;
            float bv_ = bias[col];
#pragma unroll
            for (int r = 0; r < 4; ++r) {
                int row = bm + wm + mi * 16 + quad * 4 + r;
                out[(size_t)row * N + col] = acc[mi][nj][r] + bv_;
            }
        }
}

// ---------------------------------------------------------------------------
// Flash attention v8: 2 query sub-blocks per wave (LDS-frag reuse x2).
//  Each K/V fragment read from LDS feeds TWO MFMA32s: 32 MFMA per 16 frag
//  reads per tile — halves LDS bytes/MFMA.  512 blocks (2/CU) -> dbuf +
//  async-stage pipeline kept (TLP alone no longer hides HBM latency).
//  One lgkmcnt barrier per tile; vmcnt NOT drained in loop.
// Split-K(2), stride-68 LDS (conflict-free), no-max softmax, q pre-scaled
// by 0.125*log2(e) -> exp2. LDS 34.8 KB.
// ---------------------------------------------------------------------------
__global__ __launch_bounds__(256, 2) void attn8(const bf16_t* __restrict__ qo,
                                                const bf16_t* __restrict__ ko,
                                                const bf16_t* __restrict__ vT,
                                                bf16_t* __restrict__ Op,
                                                float* __restrict__ lpp) {
    constexpr int L = 2048, D = 1024, ST = 68;
    constexpr int BUF = 2 * 64 * ST;  // one (K,V) buffer pair: 8704 elems
    __shared__ __attribute__((aligned(16))) bf16_t smem[2 * BUF];  // 34.8 KB

    const int tid = threadIdx.x, wave = tid >> 6, lane = tid & 63;
    const int l31 = lane & 31, hi = lane >> 5;
    const int b = blockIdx.x >> 4, h = blockIdx.x & 15;
    const int q0 = blockIdx.y * 256;
    const int split = blockIdx.z;
    bf16_t* Opart = Op + (size_t)split * 4194304;
    float* lpart = lpp + split * 65536;

    // staging indices: thread -> (row 0..63, 16-elem column group 0..3)
    const int rloc = tid >> 2, cg = tid & 3;
    const bf16_t* kbase = ko + ((size_t)b * L + rloc) * D + h * 64 + cg * 16;
    const bf16_t* vbase = vT + (((size_t)b * 16 + h) * 64 + rloc) * L + cg * 16;

    // ---- Q fragments, two sub-blocks (B-operand layout: lane = query) ----
    bf16x8 qfa[4], qfb[4];
    {
        const bf16_t* qa = qo + ((size_t)b * L + q0 + wave * 32 + l31) * D + h * 64 + hi * 8;
        const bf16_t* qb2 = qa + (size_t)128 * D;
#pragma unroll
        for (int ks = 0; ks < 4; ++ks) {
            qfa[ks] = *(const bf16x8*)(qa + ks * 16);
            qfb[ks] = *(const bf16x8*)(qb2 + ks * 16);
        }
    }

    f32x16 o0a{}, o1a{}, o0b{}, o1b{};  // O^T: lane = query, reg/hi = d
    float lpla = 0.f, lplb = 0.f;       // per-lane (query) partial row sums

    const int kt0 = split * 16, kt1 = kt0 + 16;

    uint4 ka, kc, va, vc;  // staging regs (one tile in flight)
    auto gload = [&](int kt) {
        const size_t koff = (size_t)(kt * 64) * D;
        const int voff = kt * 64;
        ka = *(const uint4*)(kbase + koff);
        kc = *(const uint4*)(kbase + koff + 8);
        va = *(const uint4*)(vbase + voff);
        vc = *(const uint4*)(vbase + voff + 8);
    };
    auto swrite = [&](bf16_t* buf) {
        bf16_t* kd = &buf[rloc * ST + cg * 16];
        bf16_t* vd = &buf[64 * ST + rloc * ST + cg * 16];
        *(uint2*)(kd + 0)  = make_uint2(ka.x, ka.y);
        *(uint2*)(kd + 4)  = make_uint2(ka.z, ka.w);
        *(uint2*)(kd + 8)  = make_uint2(kc.x, kc.y);
        *(uint2*)(kd + 12) = make_uint2(kc.z, kc.w);
        *(uint2*)(vd + 0)  = make_uint2(va.x, va.y);
        *(uint2*)(vd + 4)  = make_uint2(va.z, va.w);
        *(uint2*)(vd + 8)  = make_uint2(vc.x, vc.y);
        *(uint2*)(vd + 12) = make_uint2(vc.z, vc.w);
    };

    // prologue: tile kt0 -> buf0; tile kt0+1 issued (arrives during iter 0)
    gload(kt0);
    swrite(smem);
    gload(kt0 + 1 < kt1 ? kt0 + 1 : kt1 - 1);
    asm volatile("s_waitcnt lgkmcnt(0)" ::: "memory");
    __builtin_amdgcn_s_barrier();

    int cur = 0;
    for (int kt = kt0; kt < kt1; ++kt) {
        // write the arrived next tile into the other buffer, issue kt+2;
        // both overlap this tile's MFMA/VALU below.
        swrite(smem + (cur ^ 1) * BUF);
        gload(kt + 2 < kt1 ? kt + 2 : kt1 - 1);  // clamped (redundant at tail)
        const bf16_t* ksm = smem + cur * BUF;
        const bf16_t* vsm = ksm + 64 * ST;

        // ---- S^T = K Q^T : each k frag feeds both q sub-blocks ----
        f32x16 s0a{}, s1a{}, s0b{}, s1b{};
        __builtin_amdgcn_s_setprio(1);
#pragma unroll
        for (int ks = 0; ks < 4; ++ks) {
            bf16x8 k0 = ld_frag68(&ksm[l31 * ST + ks * 16 + hi * 8]);
            bf16x8 k1 = ld_frag68(&ksm[(32 + l31) * ST + ks * 16 + hi * 8]);
            s0a = MFMA32(k0, qfa[ks], s0a);
            s1a = MFMA32(k1, qfa[ks], s1a);
            s0b = MFMA32(k0, qfb[ks], s0b);
            s1b = MFMA32(k1, qfb[ks], s1b);
        }
        __builtin_amdgcn_s_setprio(0);

        // ---- p = exp2(s) -> P^T B-frags; O^T += V^T P^T (v frags x2) ----
#pragma unroll
        for (int t = 0; t < 4; ++t) {
            union { bf16x8 v; bf16_t e[8]; } pfa, pfb;
#pragma unroll
            for (int j = 0; j < 8; ++j) {
                float sva = (t < 2) ? s0a[(t & 1) * 8 + j] : s1a[(t & 1) * 8 + j];
                float svb = (t < 2) ? s0b[(t & 1) * 8 + j] : s1b[(t & 1) * 8 + j];
                float pa = __builtin_amdgcn_exp2f(sva);
                float pb = __builtin_amdgcn_exp2f(svb);
                lpla += pa; lplb += pb;
                pfa.e[j] = (bf16_t)pa;
                pfb.e[j] = (bf16_t)pb;
            }
            bf16x8 v0 = ld_frag68(&vsm[l31 * ST + t * 16 + hi * 8]);
            bf16x8 v1 = ld_frag68(&vsm[(32 + l31) * ST + t * 16 + hi * 8]);
            __builtin_amdgcn_s_setprio(1);
            o0a = MFMA32(v0, pfa.v, o0a);
            o1a = MFMA32(v1, pfa.v, o1a);
            o0b = MFMA32(v0, pfb.v, o0b);
            o1b = MFMA32(v1, pfb.v, o1b);
            __builtin_amdgcn_s_setprio(0);
        }

        // drain ds ops only (NOT vmcnt: kt+2 loads stay in flight)
        asm volatile("s_waitcnt lgkmcnt(0)" ::: "memory");
        __builtin_amdgcn_s_barrier();
        cur ^= 1;
    }

    // ---- complete per-query row sums (hi halves hold disjoint keys) ----
    lpla += __shfl_xor(lpla, 32, 64);
    lplb += __shfl_xor(lplb, 32, 64);
    if (hi == 0) {
        lpart[((size_t)b * 16 + h) * 2048 + q0 + wave * 32 + l31] = lpla;
        lpart[((size_t)b * 16 + h) * 2048 + q0 + 128 + wave * 32 + l31] = lplb;
    }

    // ---- transpose O^T -> row-major via wave-private LDS, store x2 ----
    __syncthreads();  // all waves done with K/V buffers
    bf16_t* ew = smem + wave * (32 * ST);
#pragma unroll
    for (int r = 0; r < 16; r += 2) {
        int d = (r & 3) + 8 * (r >> 2) + 4 * hi;
        *(bf16x2*)&ew[l31 * ST + d] = bf16x2{(bf16_t)o0a[r], (bf16_t)o0a[r + 1]};
        *(bf16x2*)&ew[l31 * ST + 32 + d] = bf16x2{(bf16_t)o1a[r], (bf16_t)o1a[r + 1]};
    }
    // wave-private region: compiler's lgkmcnt ordering covers RAW/WAR
#pragma unroll
    for (int p = 0; p < 4; ++p) {
        int rr = p * 8 + (lane >> 3);
        int cc = (lane & 7) * 8;
        uint2 lo = *(const uint2*)&ew[rr * ST + cc];
        uint2 hi2 = *(const uint2*)&ew[rr * ST + cc + 4];
        *(uint4*)&Opart[((size_t)b * L + q0 + wave * 32 + rr) * D + h * 64 + cc] =
            make_uint4(lo.x, lo.y, hi2.x, hi2.y);
    }
#pragma unroll
    for (int r = 0; r < 16; r += 2) {
        int d = (r & 3) + 8 * (r >> 2) + 4 * hi;
        *(bf16x2*)&ew[l31 * ST + d] = bf16x2{(bf16_t)o0b[r], (bf16_t)o0b[r + 1]};
        *(bf16x2*)&ew[l31 * ST + 32 + d] = bf16x2{(bf16_t)o1b[r], (bf16_t)o1b[r + 1]};
    }
#pragma unroll
    for (int p = 0; p < 4; ++p) {
        int rr = p * 8 + (lane >> 3);
        int cc = (lane & 7) * 8;
        uint2 lo = *(const uint2*)&ew[rr * ST + cc];
        uint2 hi2 = *(const uint2*)&ew[rr * ST + cc + 4];
        *(uint4*)&Opart[((size_t)b * L + q0 + 128 + wave * 32 + rr) * D + h * 64 + cc] =
            make_uint4(lo.x, lo.y, hi2.x, hi2.y);
    }
}

// ---------------------------------------------------------------------------
extern "C" void kernel_launch(void* const* d_in, const int* in_sizes, int n_in,
                              void* d_out, int out_size, void* d_ws, size_t ws_size,
                              hipStream_t stream) {
    const float* Q  = (const float*)d_in[0];
    const float* Kx = (const float*)d_in[1];
    const float* V  = (const float*)d_in[2];
    const float* Wq = (const float*)d_in[3];
    const float* bq = (const float*)d_in[4];
    const float* Wk = (const float*)d_in[5];
    const float* bk = (const float*)d_in[6];
    const float* Wv = (const float*)d_in[7];
    const float* bv = (const float*)d_in[8];
    const float* Wo = (const float*)d_in[9];
    const float* bo = (const float*)d_in[10];

    // ws (bf16 elems), 40 MiB total:
    //  [0,4M)      Qb   -> after qkv: Op0
    //  [4M,8M)     Kb   -> after qkv: Op1
    //  [8M,12M)    Vb   (dead after qkv)
    //  [12M,~12.8M) Wqb -> after qkv: lp partials (131072 fp32)
    //  [13M,14M)   Wkb   [13631488]
    //  [14M,15M)   Wvb   [14680064]
    //  [15M,16M)   Wob   [15728640] (live until out_gemm)
    //  [16M,20M)   vT    [16777216]
    bf16_t* ws0 = (bf16_t*)d_ws;
    bf16_t* Qb  = ws0;
    bf16_t* Kb  = ws0 + 4194304;
    bf16_t* Vb  = ws0 + 8388608;
    bf16_t* Wqb = ws0 + 12582912;
    bf16_t* Wkb = ws0 + 13631488;
    bf16_t* Wvb = ws0 + 14680064;
    bf16_t* Wob = ws0 + 15728640;
    bf16_t* vT  = ws0 + 16777216;
    bf16_t* Op  = Qb;                   // 2 x 4M bf16 partials
    float*  lpp = (float*)Wqb;          // 2 x 65536 fp32
    bf16_t* qo = (bf16_t*)d_out;        // parked in d_out, dead before out_gemm
    bf16_t* ko = qo + 4194304;

    convert_all<<<8192, 256, 0, stream>>>(Q, Kx, V, Wq, Wk, Wv, Wo, ws0);
    qkv_gemm<<<dim3(32, 8, 3), 128, 0, stream>>>(Qb, Kb, Vb, Wqb, Wkb, Wvb,
                                                 bq, bk, bv, qo, ko, vT);
    attn8<<<dim3(32, 8, 2), 256, 0, stream>>>(qo, ko, vT, Op, lpp);
    out_gemm<<<dim3(64, 8), 256, 0, stream>>>(Op, lpp, Wob, bo, (float*)d_out);
}

// Round 8
// 221.063 us; speedup vs baseline: 1.0809x; 1.0809x over previous
//
#include <hip/hip_runtime.h>
#include <math.h>
#include <stdint.h>

typedef __bf16 bf16_t;
typedef __attribute__((ext_vector_type(2))) __bf16 bf16x2;
typedef __attribute__((ext_vector_type(8))) __bf16 bf16x8;
typedef __attribute__((ext_vector_type(4))) float f32x4;
typedef __attribute__((ext_vector_type(16))) float f32x16;
typedef __attribute__((address_space(1))) unsigned int gu32;
typedef __attribute__((address_space(3))) unsigned int lu32;

#define MFMA16(a, b, c) __builtin_amdgcn_mfma_f32_16x16x32_bf16((a), (b), (c), 0, 0, 0)
#define MFMA32(a, b, c) __builtin_amdgcn_mfma_f32_32x32x16_bf16((a), (b), (c), 0, 0, 0)

// async global->LDS, 16 B per lane (wave-uniform base, lane i at base+i*16).
__device__ __forceinline__ void gll16(const void* g, void* l) {
    __builtin_amdgcn_global_load_lds((const gu32*)(uintptr_t)g,
                                     (lu32*)(uintptr_t)l, 16, 0, 0);
}

// fragment load from 8-B-aligned (stride-68) LDS rows: two ds_read_b64.
__device__ __forceinline__ bf16x8 ld_frag68(const bf16_t* p) {
    union { bf16x8 v; uint2 u[2]; } r;
    r.u[0] = *(const uint2*)p;
    r.u[1] = *(const uint2*)(p + 4);
    return r.v;
}

// ---------------------------------------------------------------------------
// convert 7 fp32 tensors -> one contiguous bf16 region in ws.
// ---------------------------------------------------------------------------
__global__ __launch_bounds__(256) void convert_all(
    const float* __restrict__ Q, const float* __restrict__ K, const float* __restrict__ V,
    const float* __restrict__ Wq, const float* __restrict__ Wk, const float* __restrict__ Wv,
    const float* __restrict__ Wo, bf16_t* __restrict__ dst) {
    size_t e0 = (size_t)blockIdx.x * 2048;
    const float* src; size_t off;
    if (e0 < 4194304)       { src = Q;  off = e0; }
    else if (e0 < 8388608)  { src = K;  off = e0 - 4194304; }
    else if (e0 < 12582912) { src = V;  off = e0 - 8388608; }
    else if (e0 < 13631488) { src = Wq; off = e0 - 12582912; }
    else if (e0 < 14680064) { src = Wk; off = e0 - 13631488; }
    else if (e0 < 15728640) { src = Wv; off = e0 - 14680064; }
    else                    { src = Wo; off = e0 - 15728640; }
#pragma unroll
    for (int p = 0; p < 2; ++p) {
        int t = p * 1024 + threadIdx.x * 4;
        float4 v = *(const float4*)(src + off + t);
        union { ushort4 u; bf16_t h[4]; } pk;
        pk.h[0] = (bf16_t)v.x; pk.h[1] = (bf16_t)v.y;
        pk.h[2] = (bf16_t)v.z; pk.h[3] = (bf16_t)v.w;
        *(ushort4*)(dst + e0 + t) = pk.u;
    }
}

// ---------------------------------------------------------------------------
// Fused QKV NT-GEMM — r3 best-measured config: dbuf 2-phase + T2 XOR
// swizzle, 256 threads, 4 waves, wave tile 64x64.  (A/B history: serial+
// conflicts 15.0 MfmaUtil; dbuf 15.3; dbuf+T2 21.6 = 586 TF ~= the m233
// 2-phase structural ceiling; single-buf+T2 18.2; 2-wave-wide 14.7.)
//   LDS [128][64] bf16; 16B-slot s of row r holds GLOBAL slot s^(r&7).
//   Stage: linear gll16 dest, source col pre-swizzled: (l&7)^(l>>3).
//   Read:  slot = ((ks>>3)+quad) ^ (row&7); residual 2-way = free.
// grid (32, 8, 3): x = M-tile.
// z=0: qo scaled by 0.125*log2(e).  z=1: ko natural order.
// z=2: vT[b][h][d][sigma(l)], sigma swaps key-index bits 2<->3.
// ---------------------------------------------------------------------------
__global__ __launch_bounds__(256) void qkv_gemm(
    const bf16_t* __restrict__ Qb, const bf16_t* __restrict__ Kb, const bf16_t* __restrict__ Vb,
    const bf16_t* __restrict__ Wqb, const bf16_t* __restrict__ Wkb, const bf16_t* __restrict__ Wvb,
    const float* __restrict__ bq, const float* __restrict__ bk, const float* __restrict__ bv,
    bf16_t* __restrict__ qo, bf16_t* __restrict__ ko, bf16_t* __restrict__ vT) {
    constexpr int Kdim = 1024, N = 1024;
    // double buffer: buf b at smem + b*16384 (A 8192 elems, then B 8192)
    __shared__ __attribute__((aligned(16))) bf16_t smem[4 * 128 * 64];  // 64 KiB

    const int tid = threadIdx.x, wave = tid >> 6, lane = tid & 63;
    const int z = blockIdx.z;
    const bf16_t* A = (z == 0) ? Qb : (z == 1) ? Kb : Vb;
    const bf16_t* W = (z == 0) ? Wqb : (z == 1) ? Wkb : Wvb;
    const float* bias = (z == 0) ? bq : (z == 1) ? bk : bv;
    const int bm = blockIdx.x * 128, bn = blockIdx.y * 128;
    const int l16 = lane & 15, quad = lane >> 4;
    const int wm = (wave >> 1) * 64, wn = (wave & 1) * 64;
    const int grow = lane >> 3;                       // 0..7 == row&7 in chunk
    const int gcol = (((lane & 7) ^ grow)) * 8;       // inverse-swizzled source
    const int rsw = l16 & 7;                          // read-side row swizzle

    f32x4 acc[4][4] = {};

    auto stage = [&](int k0, bf16_t* As, bf16_t* Bs) {
#pragma unroll
        for (int j = 0; j < 4; ++j) {
            int chunk = wave * 4 + j;
            int row = chunk * 8 + grow;
            gll16(A + (size_t)(bm + row) * Kdim + k0 + gcol, As + chunk * 512);
            gll16(W + (size_t)(bn + row) * Kdim + k0 + gcol, Bs + chunk * 512);
        }
    };
    auto compute = [&](const bf16_t* As, const bf16_t* Bs) {
#pragma unroll
        for (int ks = 0; ks < 64; ks += 32) {
            const int so = (((ks >> 3) + quad) ^ rsw) * 8;
            bf16x8 af[4], bf[4];
#pragma unroll
            for (int i = 0; i < 4; ++i)
                af[i] = *(const bf16x8*)&As[(wm + i * 16 + l16) * 64 + so];
#pragma unroll
            for (int i = 0; i < 4; ++i)
                bf[i] = *(const bf16x8*)&Bs[(wn + i * 16 + l16) * 64 + so];
#pragma unroll
            for (int i = 0; i < 4; ++i)
#pragma unroll
                for (int j = 0; j < 4; ++j)
                    acc[i][j] = MFMA16(af[i], bf[j], acc[i][j]);
        }
    };

    stage(0, smem, smem + 8192);
    asm volatile("s_waitcnt vmcnt(0)" ::: "memory");
    __builtin_amdgcn_s_barrier();
    int cur = 0;
    for (int t = 0; t < 15; ++t) {
        bf16_t* nb = smem + (cur ^ 1) * 16384;
        stage((t + 1) * 64, nb, nb + 8192);        // next tile in flight
        bf16_t* cb = smem + cur * 16384;
        compute(cb, cb + 8192);                    // MFMA hides load latency
        asm volatile("s_waitcnt vmcnt(0)" ::: "memory");
        __builtin_amdgcn_s_barrier();
        cur ^= 1;
    }
    {
        bf16_t* cb = smem + cur * 16384;
        compute(cb, cb + 8192);
    }

    if (z < 2) {
        bf16_t* outp = (z == 0) ? qo : ko;
        const float sc = (z == 0) ? 0.18033688011112042f : 1.0f;
        constexpr int RST = 132;  // repack row stride (66 dw: 2-way max on wr)
#pragma unroll
        for (int p = 0; p < 2; ++p) {  // row halves [64p, 64p+64)
            __syncthreads();
            if ((wave >> 1) == p) {
#pragma unroll
                for (int mi = 0; mi < 4; ++mi)
#pragma unroll
                    for (int nj = 0; nj < 4; ++nj) {
                        int col = wn + nj * 16 + l16;
                        float bv_ = bias[bn + col];
#pragma unroll
                        for (int r = 0; r < 4; ++r) {
                            int rp = mi * 16 + quad * 4 + r;
                            smem[rp * RST + col] = (bf16_t)((acc[mi][nj][r] + bv_) * sc);
                        }
                    }
            }
            __syncthreads();
            // cooperative coalesced store: 64 rows x 128 cols
            int rp = tid >> 2;
            int cb2 = (tid & 3) * 32;
            int row = bm + p * 64 + rp;
#pragma unroll
            for (int j = 0; j < 4; ++j) {
                uint2 lo = *(const uint2*)&smem[rp * RST + cb2 + j * 8];
                uint2 hi = *(const uint2*)&smem[rp * RST + cb2 + j * 8 + 4];
                *(uint4*)&outp[(size_t)row * N + bn + cb2 + j * 8] =
                    make_uint4(lo.x, lo.y, hi.x, hi.y);
            }
        }
    } else {
#pragma unroll
        for (int mi = 0; mi < 4; ++mi)
#pragma unroll
            for (int nj = 0; nj < 4; ++nj) {
                int col = bn + wn + nj * 16 + l16;
                int h = col >> 6, d = col & 63;
                float bv_ = bias[col];
                int row0 = bm + wm + mi * 16 + quad * 4;
                int bb = row0 >> 11, l = row0 & 2047;
                // sigma: swap key-index bits 2<->3 (4-aligned blocks preserved)
                int lb = (l & ~12) | ((l & 4) << 1) | ((l & 8) >> 1);
                union { ushort4 u; bf16_t h4[4]; } pk;
#pragma unroll
                for (int r = 0; r < 4; ++r) pk.h4[r] = (bf16_t)(acc[mi][nj][r] + bv_);
                *(ushort4*)&vT[(((size_t)bb * 16 + h) * 64 + d) * 2048 + lb] = pk.u;
            }
    }
}

// ---------------------------------------------------------------------------
// Out-projection GEMM with FUSED softmax-normalize (absorbs old `combine`):
//   A = (Op0 + Op1) * (1/(lp0+lp1)) computed in registers during staging
//   (reg-staged A replicating gll16's exact LDS layout; W stays gll16).
//   dbuf + T2 swizzle. grid (64, 8). k0 window == one head block (h=k0>>6),
//   so the lp index is per-row uniform within a staging chunk.
// ---------------------------------------------------------------------------
__global__ __launch_bounds__(256) void out_gemm(const bf16_t* __restrict__ Op,
                                                const float* __restrict__ lpp,
                                                const bf16_t* __restrict__ W,
                                                const float* __restrict__ bias,
                                                float* __restrict__ out) {
    constexpr int Kdim = 1024, N = 1024;
    // buf b at smem + b*12288: A 4096 elems (64x64), B 8192 elems (128x64)
    __shared__ __attribute__((aligned(16))) bf16_t smem[2 * 12288];  // 48 KiB
    const int tid = threadIdx.x, wave = tid >> 6, lane = tid & 63;
    const int bm = blockIdx.x * 64, bn = blockIdx.y * 128;
    const int l16 = lane & 15, quad = lane >> 4;
    const int wm = (wave >> 1) * 32, wn = (wave & 1) * 64;
    const int grow = lane >> 3;
    const int gcol = (((lane & 7) ^ grow)) * 8;
    const int rsw = l16 & 7;
    f32x4 acc[2][4] = {};

    // per-lane A rows for the wave's two 8-row chunks
    const int arow0 = bm + (wave * 2 + 0) * 8 + grow;
    const int arow1 = bm + (wave * 2 + 1) * 8 + grow;

    uint4 a0p, a0q, a1p, a1q;   // Op0/Op1 16B chunks for the two rows
    float ivn0, ivn1;           // 1/(lp0+lp1) per row (h = k0>>6 uniform)

    auto loadA = [&](int k0) {
        const int h = k0 >> 6;
        a0p = *(const uint4*)(Op + (size_t)arow0 * Kdim + k0 + gcol);
        a0q = *(const uint4*)(Op + 4194304 + (size_t)arow0 * Kdim + k0 + gcol);
        a1p = *(const uint4*)(Op + (size_t)arow1 * Kdim + k0 + gcol);
        a1q = *(const uint4*)(Op + 4194304 + (size_t)arow1 * Kdim + k0 + gcol);
        const int li0 = ((arow0 >> 11) * 16 + h) * 2048 + (arow0 & 2047);
        const int li1 = ((arow1 >> 11) * 16 + h) * 2048 + (arow1 & 2047);
        ivn0 = 1.f / (lpp[li0] + lpp[65536 + li0]);
        ivn1 = 1.f / (lpp[li1] + lpp[65536 + li1]);
    };
    auto writeA = [&](bf16_t* As) {
        union { uint4 u; bf16_t h8[8]; } x, y, w0, w1;
        x.u = a0p; y.u = a0q;
#pragma unroll
        for (int i = 0; i < 8; ++i)
            w0.h8[i] = (bf16_t)(((float)x.h8[i] + (float)y.h8[i]) * ivn0);
        x.u = a1p; y.u = a1q;
#pragma unroll
        for (int i = 0; i < 8; ++i)
            w1.h8[i] = (bf16_t)(((float)x.h8[i] + (float)y.h8[i]) * ivn1);
        *(uint4*)&As[(wave * 2 + 0) * 512 + lane * 8] = w0.u;
        *(uint4*)&As[(wave * 2 + 1) * 512 + lane * 8] = w1.u;
    };
    auto stageW = [&](int k0, bf16_t* Bs) {
#pragma unroll
        for (int j = 0; j < 4; ++j) {
            int chunk = wave * 4 + j;
            int row = chunk * 8 + grow;
            gll16(W + (size_t)(bn + row) * Kdim + k0 + gcol, Bs + chunk * 512);
        }
    };
    auto compute = [&](const bf16_t* As, const bf16_t* Bs) {
#pragma unroll
        for (int ks = 0; ks < 64; ks += 32) {
            const int so0 = (((ks >> 3) + quad) ^ rsw) * 8;
            bf16x8 af[2], bf[4];
#pragma unroll
            for (int i = 0; i < 2; ++i)
                af[i] = *(const bf16x8*)&As[(wm + i * 16 + l16) * 64 + so0];
#pragma unroll
            for (int i = 0; i < 4; ++i)
                bf[i] = *(const bf16x8*)&Bs[(wn + i * 16 + l16) * 64 + so0];
#pragma unroll
            for (int i = 0; i < 2; ++i)
#pragma unroll
                for (int j = 0; j < 4; ++j)
                    acc[i][j] = MFMA16(af[i], bf[j], acc[i][j]);
        }
    };

    // prologue: tile 0 -> buf0
    loadA(0);
    stageW(0, smem + 4096);
    writeA(smem);            // compiler waits vmcnt for a-regs only
    __syncthreads();         // drains gll16 (vmcnt 0) + ds writes, barrier
    int cur = 0;
    for (int t = 0; t < 15; ++t) {
        bf16_t* nb = smem + (cur ^ 1) * 12288;
        loadA((t + 1) * 64);           // A regs for next tile (in flight)
        stageW((t + 1) * 64, nb + 4096);  // W gll16 for next tile (in flight)
        bf16_t* cb = smem + cur * 12288;
        compute(cb, cb + 4096);        // MFMA hides both
        writeA(nb);                    // waits only the a-regs, not gll16
        asm volatile("s_waitcnt vmcnt(0)" ::: "memory");
        __syncthreads();
        cur ^= 1;
    }
    {
        bf16_t* cb = smem + cur * 12288;
        compute(cb, cb + 4096);
    }

#pragma unroll
    for (int mi = 0; mi < 2; ++mi)
#pragma unroll
        for (int nj = 0; nj < 4; ++nj) {
            int col = bn + wn + nj * 16 + l16;
            float bv_ = bias[col];
#pragma unroll
            for (int r = 0; r < 4; ++r) {
                int row = bm + wm + mi * 16 + quad * 4 + r;
                out[(size_t)row * N + col] = acc[mi][nj][r] + bv_;
            }
        }
}

// ---------------------------------------------------------------------------
// Flash attention v8: 2 query sub-blocks per wave (LDS-frag reuse x2).
//  Each K/V fragment read from LDS feeds TWO MFMA32s: 32 MFMA per 16 frag
//  reads per tile — halves LDS bytes/MFMA.  512 blocks (2/CU) -> dbuf +
//  async-stage pipeline kept (TLP alone no longer hides HBM latency).
//  One lgkmcnt barrier per tile; vmcnt NOT drained in loop.
// Split-K(2), stride-68 LDS (conflict-free), no-max softmax, q pre-scaled
// by 0.125*log2(e) -> exp2. LDS 34.8 KB.
// ---------------------------------------------------------------------------
__global__ __launch_bounds__(256, 2) void attn8(const bf16_t* __restrict__ qo,
                                                const bf16_t* __restrict__ ko,
                                                const bf16_t* __restrict__ vT,
                                                bf16_t* __restrict__ Op,
                                                float* __restrict__ lpp) {
    constexpr int L = 2048, D = 1024, ST = 68;
    constexpr int BUF = 2 * 64 * ST;  // one (K,V) buffer pair: 8704 elems
    __shared__ __attribute__((aligned(16))) bf16_t smem[2 * BUF];  // 34.8 KB

    const int tid = threadIdx.x, wave = tid >> 6, lane = tid & 63;
    const int l31 = lane & 31, hi = lane >> 5;
    const int b = blockIdx.x >> 4, h = blockIdx.x & 15;
    const int q0 = blockIdx.y * 256;
    const int split = blockIdx.z;
    bf16_t* Opart = Op + (size_t)split * 4194304;
    float* lpart = lpp + split * 65536;

    // staging indices: thread -> (row 0..63, 16-elem column group 0..3)
    const int rloc = tid >> 2, cg = tid & 3;
    const bf16_t* kbase = ko + ((size_t)b * L + rloc) * D + h * 64 + cg * 16;
    const bf16_t* vbase = vT + (((size_t)b * 16 + h) * 64 + rloc) * L + cg * 16;

    // ---- Q fragments, two sub-blocks (B-operand layout: lane = query) ----
    bf16x8 qfa[4], qfb[4];
    {
        const bf16_t* qa = qo + ((size_t)b * L + q0 + wave * 32 + l31) * D + h * 64 + hi * 8;
        const bf16_t* qb2 = qa + (size_t)128 * D;
#pragma unroll
        for (int ks = 0; ks < 4; ++ks) {
            qfa[ks] = *(const bf16x8*)(qa + ks * 16);
            qfb[ks] = *(const bf16x8*)(qb2 + ks * 16);
        }
    }

    f32x16 o0a{}, o1a{}, o0b{}, o1b{};  // O^T: lane = query, reg/hi = d
    float lpla = 0.f, lplb = 0.f;       // per-lane (query) partial row sums

    const int kt0 = split * 16, kt1 = kt0 + 16;

    uint4 ka, kc, va, vc;  // staging regs (one tile in flight)
    auto gload = [&](int kt) {
        const size_t koff = (size_t)(kt * 64) * D;
        const int voff = kt * 64;
        ka = *(const uint4*)(kbase + koff);
        kc = *(const uint4*)(kbase + koff + 8);
        va = *(const uint4*)(vbase + voff);
        vc = *(const uint4*)(vbase + voff + 8);
    };
    auto swrite = [&](bf16_t* buf) {
        bf16_t* kd = &buf[rloc * ST + cg * 16];
        bf16_t* vd = &buf[64 * ST + rloc * ST + cg * 16];
        *(uint2*)(kd + 0)  = make_uint2(ka.x, ka.y);
        *(uint2*)(kd + 4)  = make_uint2(ka.z, ka.w);
        *(uint2*)(kd + 8)  = make_uint2(kc.x, kc.y);
        *(uint2*)(kd + 12) = make_uint2(kc.z, kc.w);
        *(uint2*)(vd + 0)  = make_uint2(va.x, va.y);
        *(uint2*)(vd + 4)  = make_uint2(va.z, va.w);
        *(uint2*)(vd + 8)  = make_uint2(vc.x, vc.y);
        *(uint2*)(vd + 12) = make_uint2(vc.z, vc.w);
    };

    // prologue: tile kt0 -> buf0; tile kt0+1 issued (arrives during iter 0)
    gload(kt0);
    swrite(smem);
    gload(kt0 + 1 < kt1 ? kt0 + 1 : kt1 - 1);
    asm volatile("s_waitcnt lgkmcnt(0)" ::: "memory");
    __builtin_amdgcn_s_barrier();

    int cur = 0;
    for (int kt = kt0; kt < kt1; ++kt) {
        // write the arrived next tile into the other buffer, issue kt+2;
        // both overlap this tile's MFMA/VALU below.
        swrite(smem + (cur ^ 1) * BUF);
        gload(kt + 2 < kt1 ? kt + 2 : kt1 - 1);  // clamped (redundant at tail)
        const bf16_t* ksm = smem + cur * BUF;
        const bf16_t* vsm = ksm + 64 * ST;

        // ---- S^T = K Q^T : each k frag feeds both q sub-blocks ----
        f32x16 s0a{}, s1a{}, s0b{}, s1b{};
        __builtin_amdgcn_s_setprio(1);
#pragma unroll
        for (int ks = 0; ks < 4; ++ks) {
            bf16x8 k0 = ld_frag68(&ksm[l31 * ST + ks * 16 + hi * 8]);
            bf16x8 k1 = ld_frag68(&ksm[(32 + l31) * ST + ks * 16 + hi * 8]);
            s0a = MFMA32(k0, qfa[ks], s0a);
            s1a = MFMA32(k1, qfa[ks], s1a);
            s0b = MFMA32(k0, qfb[ks], s0b);
            s1b = MFMA32(k1, qfb[ks], s1b);
        }
        __builtin_amdgcn_s_setprio(0);

        // ---- p = exp2(s) -> P^T B-frags; O^T += V^T P^T (v frags x2) ----
#pragma unroll
        for (int t = 0; t < 4; ++t) {
            union { bf16x8 v; bf16_t e[8]; } pfa, pfb;
#pragma unroll
            for (int j = 0; j < 8; ++j) {
                float sva = (t < 2) ? s0a[(t & 1) * 8 + j] : s1a[(t & 1) * 8 + j];
                float svb = (t < 2) ? s0b[(t & 1) * 8 + j] : s1b[(t & 1) * 8 + j];
                float pa = __builtin_amdgcn_exp2f(sva);
                float pb = __builtin_amdgcn_exp2f(svb);
                lpla += pa; lplb += pb;
                pfa.e[j] = (bf16_t)pa;
                pfb.e[j] = (bf16_t)pb;
            }
            bf16x8 v0 = ld_frag68(&vsm[l31 * ST + t * 16 + hi * 8]);
            bf16x8 v1 = ld_frag68(&vsm[(32 + l31) * ST + t * 16 + hi * 8]);
            __builtin_amdgcn_s_setprio(1);
            o0a = MFMA32(v0, pfa.v, o0a);
            o1a = MFMA32(v1, pfa.v, o1a);
            o0b = MFMA32(v0, pfb.v, o0b);
            o1b = MFMA32(v1, pfb.v, o1b);
            __builtin_amdgcn_s_setprio(0);
        }

        // drain ds ops only (NOT vmcnt: kt+2 loads stay in flight)
        asm volatile("s_waitcnt lgkmcnt(0)" ::: "memory");
        __builtin_amdgcn_s_barrier();
        cur ^= 1;
    }

    // ---- complete per-query row sums (hi halves hold disjoint keys) ----
    lpla += __shfl_xor(lpla, 32, 64);
    lplb += __shfl_xor(lplb, 32, 64);
    if (hi == 0) {
        lpart[((size_t)b * 16 + h) * 2048 + q0 + wave * 32 + l31] = lpla;
        lpart[((size_t)b * 16 + h) * 2048 + q0 + 128 + wave * 32 + l31] = lplb;
    }

    // ---- transpose O^T -> row-major via wave-private LDS, store x2 ----
    __syncthreads();  // all waves done with K/V buffers
    bf16_t* ew = smem + wave * (32 * ST);
#pragma unroll
    for (int r = 0; r < 16; r += 2) {
        int d = (r & 3) + 8 * (r >> 2) + 4 * hi;
        *(bf16x2*)&ew[l31 * ST + d] = bf16x2{(bf16_t)o0a[r], (bf16_t)o0a[r + 1]};
        *(bf16x2*)&ew[l31 * ST + 32 + d] = bf16x2{(bf16_t)o1a[r], (bf16_t)o1a[r + 1]};
    }
    // wave-private region: compiler's lgkmcnt ordering covers RAW/WAR
#pragma unroll
    for (int p = 0; p < 4; ++p) {
        int rr = p * 8 + (lane >> 3);
        int cc = (lane & 7) * 8;
        uint2 lo = *(const uint2*)&ew[rr * ST + cc];
        uint2 hi2 = *(const uint2*)&ew[rr * ST + cc + 4];
        *(uint4*)&Opart[((size_t)b * L + q0 + wave * 32 + rr) * D + h * 64 + cc] =
            make_uint4(lo.x, lo.y, hi2.x, hi2.y);
    }
#pragma unroll
    for (int r = 0; r < 16; r += 2) {
        int d = (r & 3) + 8 * (r >> 2) + 4 * hi;
        *(bf16x2*)&ew[l31 * ST + d] = bf16x2{(bf16_t)o0b[r], (bf16_t)o0b[r + 1]};
        *(bf16x2*)&ew[l31 * ST + 32 + d] = bf16x2{(bf16_t)o1b[r], (bf16_t)o1b[r + 1]};
    }
#pragma unroll
    for (int p = 0; p < 4; ++p) {
        int rr = p * 8 + (lane >> 3);
        int cc = (lane & 7) * 8;
        uint2 lo = *(const uint2*)&ew[rr * ST + cc];
        uint2 hi2 = *(const uint2*)&ew[rr * ST + cc + 4];
        *(uint4*)&Opart[((size_t)b * L + q0 + 128 + wave * 32 + rr) * D + h * 64 + cc] =
            make_uint4(lo.x, lo.y, hi2.x, hi2.y);
    }
}

// ---------------------------------------------------------------------------
extern "C" void kernel_launch(void* const* d_in, const int* in_sizes, int n_in,
                              void* d_out, int out_size, void* d_ws, size_t ws_size,
                              hipStream_t stream) {
    const float* Q  = (const float*)d_in[0];
    const float* Kx = (const float*)d_in[1];
    const float* V  = (const float*)d_in[2];
    const float* Wq = (const float*)d_in[3];
    const float* bq = (const float*)d_in[4];
    const float* Wk = (const float*)d_in[5];
    const float* bk = (const float*)d_in[6];
    const float* Wv = (const float*)d_in[7];
    const float* bv = (const float*)d_in[8];
    const float* Wo = (const float*)d_in[9];
    const float* bo = (const float*)d_in[10];

    // ws (bf16 elems), 40 MiB total:
    //  [0,4M)      Qb   -> after qkv: Op0
    //  [4M,8M)     Kb   -> after qkv: Op1
    //  [8M,12M)    Vb   (dead after qkv)
    //  [12M,~12.8M) Wqb -> after qkv: lp partials (131072 fp32)
    //  [13M,14M)   Wkb   [13631488]
    //  [14M,15M)   Wvb   [14680064]
    //  [15M,16M)   Wob   [15728640] (live until out_gemm)
    //  [16M,20M)   vT    [16777216]
    bf16_t* ws0 = (bf16_t*)d_ws;
    bf16_t* Qb  = ws0;
    bf16_t* Kb  = ws0 + 4194304;
    bf16_t* Vb  = ws0 + 8388608;
    bf16_t* Wqb = ws0 + 12582912;
    bf16_t* Wkb = ws0 + 13631488;
    bf16_t* Wvb = ws0 + 14680064;
    bf16_t* Wob = ws0 + 15728640;
    bf16_t* vT  = ws0 + 16777216;
    bf16_t* Op  = Qb;                   // 2 x 4M bf16 partials
    float*  lpp = (float*)Wqb;          // 2 x 65536 fp32
    bf16_t* qo = (bf16_t*)d_out;        // parked in d_out, dead before out_gemm
    bf16_t* ko = qo + 4194304;

    convert_all<<<8192, 256, 0, stream>>>(Q, Kx, V, Wq, Wk, Wv, Wo, ws0);
    qkv_gemm<<<dim3(32, 8, 3), 256, 0, stream>>>(Qb, Kb, Vb, Wqb, Wkb, Wvb,
                                                 bq, bk, bv, qo, ko, vT);
    attn8<<<dim3(32, 8, 2), 256, 0, stream>>>(qo, ko, vT, Op, lpp);
    out_gemm<<<dim3(64, 8), 256, 0, stream>>>(Op, lpp, Wob, bo, (float*)d_out);
}

// Round 9
// 212.917 us; speedup vs baseline: 1.1223x; 1.0383x over previous
//
#include <hip/hip_runtime.h>
#include <math.h>
#include <stdint.h>

typedef __bf16 bf16_t;
typedef __attribute__((ext_vector_type(2))) __bf16 bf16x2;
typedef __attribute__((ext_vector_type(8))) __bf16 bf16x8;
typedef __attribute__((ext_vector_type(4))) float f32x4;
typedef __attribute__((ext_vector_type(16))) float f32x16;
typedef __attribute__((address_space(1))) unsigned int gu32;
typedef __attribute__((address_space(3))) unsigned int lu32;

#define MFMA16(a, b, c) __builtin_amdgcn_mfma_f32_16x16x32_bf16((a), (b), (c), 0, 0, 0)
#define MFMA32(a, b, c) __builtin_amdgcn_mfma_f32_32x32x16_bf16((a), (b), (c), 0, 0, 0)

// async global->LDS, 16 B per lane (wave-uniform base, lane i at base+i*16).
__device__ __forceinline__ void gll16(const void* g, void* l) {
    __builtin_amdgcn_global_load_lds((const gu32*)(uintptr_t)g,
                                     (lu32*)(uintptr_t)l, 16, 0, 0);
}

// fragment load from 8-B-aligned (stride-68) LDS rows: two ds_read_b64.
__device__ __forceinline__ bf16x8 ld_frag68(const bf16_t* p) {
    union { bf16x8 v; uint2 u[2]; } r;
    r.u[0] = *(const uint2*)p;
    r.u[1] = *(const uint2*)(p + 4);
    return r.v;
}

// ---------------------------------------------------------------------------
// convert 7 fp32 tensors -> one contiguous bf16 region in ws.
// ---------------------------------------------------------------------------
__global__ __launch_bounds__(256) void convert_all(
    const float* __restrict__ Q, const float* __restrict__ K, const float* __restrict__ V,
    const float* __restrict__ Wq, const float* __restrict__ Wk, const float* __restrict__ Wv,
    const float* __restrict__ Wo, bf16_t* __restrict__ dst) {
    size_t e0 = (size_t)blockIdx.x * 2048;
    const float* src; size_t off;
    if (e0 < 4194304)       { src = Q;  off = e0; }
    else if (e0 < 8388608)  { src = K;  off = e0 - 4194304; }
    else if (e0 < 12582912) { src = V;  off = e0 - 8388608; }
    else if (e0 < 13631488) { src = Wq; off = e0 - 12582912; }
    else if (e0 < 14680064) { src = Wk; off = e0 - 13631488; }
    else if (e0 < 15728640) { src = Wv; off = e0 - 14680064; }
    else                    { src = Wo; off = e0 - 15728640; }
#pragma unroll
    for (int p = 0; p < 2; ++p) {
        int t = p * 1024 + threadIdx.x * 4;
        float4 v = *(const float4*)(src + off + t);
        union { ushort4 u; bf16_t h[4]; } pk;
        pk.h[0] = (bf16_t)v.x; pk.h[1] = (bf16_t)v.y;
        pk.h[2] = (bf16_t)v.z; pk.h[3] = (bf16_t)v.w;
        *(ushort4*)(dst + e0 + t) = pk.u;
    }
}

// ---------------------------------------------------------------------------
// Fused QKV NT-GEMM — 256x256 tile, 8-wave phase-interleaved (T3 regime).
//  512 threads, wave grid 2M x 4N, per-wave C = 128x64 (acc[8][4]).
//  Per K-tile (BK=64) per wave: 24 ds_read_b128 (minimum: B-frags held in
//  regs across both M-half phases) -> 64 MFMA; 8 gll16 front-loaded into
//  phases 0-1 (youngest load gets ~3 MFMA phases to land before the
//  end-of-tile vmcnt(0)).  One barrier per K-tile.  LDS 128 KiB dbuf,
//  1 block/CU, grid (16,4,3) = 192 blocks.
//  T2 XOR swizzle (proven): LDS 16B-slot s of row r holds GLOBAL slot
//  s^(r&7); stage linear gll16 dest + pre-swizzled source col
//  (l&7)^(l>>3); read slot = ((ks>>3)+quad)^(row&7); residual 2-way=free.
// z=0: qo scaled by 0.125*log2(e).  z=1: ko natural order.
// z=2: vT[b][h][d][sigma(l)], sigma swaps key-index bits 2<->3.
// ---------------------------------------------------------------------------
__global__ __launch_bounds__(512, 2) void qkv_gemm(
    const bf16_t* __restrict__ Qb, const bf16_t* __restrict__ Kb, const bf16_t* __restrict__ Vb,
    const bf16_t* __restrict__ Wqb, const bf16_t* __restrict__ Wkb, const bf16_t* __restrict__ Wvb,
    const float* __restrict__ bq, const float* __restrict__ bk, const float* __restrict__ bv,
    bf16_t* __restrict__ qo, bf16_t* __restrict__ ko, bf16_t* __restrict__ vT) {
    constexpr int Kdim = 1024, N = 1024;
    // buf b at smem + b*32768: A tile 256x64 (16384), then B tile (16384)
    __shared__ __attribute__((aligned(16))) bf16_t smem[2 * 32768];  // 128 KiB

    const int tid = threadIdx.x, wave = tid >> 6, lane = tid & 63;
    const int z = blockIdx.z;
    const bf16_t* A = (z == 0) ? Qb : (z == 1) ? Kb : Vb;
    const bf16_t* W = (z == 0) ? Wqb : (z == 1) ? Wkb : Wvb;
    const float* bias = (z == 0) ? bq : (z == 1) ? bk : bv;
    const int bm = blockIdx.x * 256, bn = blockIdx.y * 256;
    const int l16 = lane & 15, quad = lane >> 4;
    const int wr = wave >> 2, wc = wave & 3;
    const int wm = wr * 128, wn = wc * 64;
    const int grow = lane >> 3;                       // 0..7 == row&7 in chunk
    const int gcol = (((lane & 7) ^ grow)) * 8;       // inverse-swizzled source
    const int rsw = l16 & 7;                          // read-side row swizzle

    f32x4 acc[8][4] = {};

    // stage one operand tile (256 rows x 64 cols) = 32 chunks; wave w owns
    // chunks w*4..w*4+3 (rows w*32..w*32+31).
    auto stageA = [&](int k0, bf16_t* As) {
#pragma unroll
        for (int j = 0; j < 4; ++j) {
            int chunk = wave * 4 + j;
            int row = chunk * 8 + grow;
            gll16(A + (size_t)(bm + row) * Kdim + k0 + gcol, As + chunk * 512);
        }
    };
    auto stageB = [&](int k0, bf16_t* Bs) {
#pragma unroll
        for (int j = 0; j < 4; ++j) {
            int chunk = wave * 4 + j;
            int row = chunk * 8 + grow;
            gll16(W + (size_t)(bn + row) * Kdim + k0 + gcol, Bs + chunk * 512);
        }
    };

    stageA(0, smem);
    stageB(0, smem + 16384);
    asm volatile("s_waitcnt vmcnt(0)" ::: "memory");
    __builtin_amdgcn_s_barrier();

    int cur = 0;
    for (int t = 0; t < 16; ++t) {
        const bf16_t* cA = smem + cur * 32768;
        const bf16_t* cB = cA + 16384;
        bf16_t* nA = smem + (cur ^ 1) * 32768;
        bf16_t* nB = nA + 16384;
        const int k1 = (t + 1) * 64;
        const bool pf = (t < 15);

        bf16x8 af[4], bf[4];
        // ---- phase 0: stage A(t+1); (mh0, ks=0) ----
        if (pf) stageA(k1, nA);
        {
            const int so = ((0 + quad) ^ rsw) * 8;
#pragma unroll
            for (int i = 0; i < 4; ++i)
                bf[i] = *(const bf16x8*)&cB[(wn + i * 16 + l16) * 64 + so];
#pragma unroll
            for (int i = 0; i < 4; ++i)
                af[i] = *(const bf16x8*)&cA[(wm + i * 16 + l16) * 64 + so];
            __builtin_amdgcn_s_setprio(1);
#pragma unroll
            for (int i = 0; i < 4; ++i)
#pragma unroll
                for (int j = 0; j < 4; ++j)
                    acc[i][j] = MFMA16(af[i], bf[j], acc[i][j]);
            __builtin_amdgcn_s_setprio(0);
        }
        // ---- phase 1: stage B(t+1); (mh1, ks=0), bf reused ----
        if (pf) stageB(k1, nB);
        {
            const int so = ((0 + quad) ^ rsw) * 8;
#pragma unroll
            for (int i = 0; i < 4; ++i)
                af[i] = *(const bf16x8*)&cA[(wm + 64 + i * 16 + l16) * 64 + so];
            __builtin_amdgcn_s_setprio(1);
#pragma unroll
            for (int i = 0; i < 4; ++i)
#pragma unroll
                for (int j = 0; j < 4; ++j)
                    acc[4 + i][j] = MFMA16(af[i], bf[j], acc[4 + i][j]);
            __builtin_amdgcn_s_setprio(0);
        }
        // ---- phase 2: (mh0, ks=32) ----
        {
            const int so = ((4 + quad) ^ rsw) * 8;
#pragma unroll
            for (int i = 0; i < 4; ++i)
                bf[i] = *(const bf16x8*)&cB[(wn + i * 16 + l16) * 64 + so];
#pragma unroll
            for (int i = 0; i < 4; ++i)
                af[i] = *(const bf16x8*)&cA[(wm + i * 16 + l16) * 64 + so];
            __builtin_amdgcn_s_setprio(1);
#pragma unroll
            for (int i = 0; i < 4; ++i)
#pragma unroll
                for (int j = 0; j < 4; ++j)
                    acc[i][j] = MFMA16(af[i], bf[j], acc[i][j]);
            __builtin_amdgcn_s_setprio(0);
        }
        // ---- phase 3: (mh1, ks=32), bf reused ----
        {
            const int so = ((4 + quad) ^ rsw) * 8;
#pragma unroll
            for (int i = 0; i < 4; ++i)
                af[i] = *(const bf16x8*)&cA[(wm + 64 + i * 16 + l16) * 64 + so];
            __builtin_amdgcn_s_setprio(1);
#pragma unroll
            for (int i = 0; i < 4; ++i)
#pragma unroll
                for (int j = 0; j < 4; ++j)
                    acc[4 + i][j] = MFMA16(af[i], bf[j], acc[4 + i][j]);
            __builtin_amdgcn_s_setprio(0);
        }

        asm volatile("s_waitcnt vmcnt(0)" ::: "memory");  // tile t+1 landed
        __builtin_amdgcn_s_barrier();
        cur ^= 1;
    }

    if (z < 2) {
        bf16_t* outp = (z == 0) ? qo : ko;
        const float sc = (z == 0) ? 0.18033688011112042f : 1.0f;
        constexpr int RST = 264;  // repack row stride (132 dw: 2-way max on wr)
#pragma unroll
        for (int p = 0; p < 2; ++p) {  // row halves [128p, 128p+128)
            __syncthreads();
            if (wr == p) {
#pragma unroll
                for (int mi = 0; mi < 8; ++mi)
#pragma unroll
                    for (int nj = 0; nj < 4; ++nj) {
                        int col = wn + nj * 16 + l16;         // 0..255
                        float bv_ = bias[bn + col];
#pragma unroll
                        for (int r = 0; r < 4; ++r) {
                            int rp = mi * 16 + quad * 4 + r;  // 0..127
                            smem[rp * RST + col] = (bf16_t)((acc[mi][nj][r] + bv_) * sc);
                        }
                    }
            }
            __syncthreads();
            // cooperative coalesced store: 128 rows x 256 cols, 512 threads
            int rp = tid >> 2;
            int cb2 = (tid & 3) * 64;
            int row = bm + p * 128 + rp;
#pragma unroll
            for (int j = 0; j < 8; ++j) {
                uint2 lo = *(const uint2*)&smem[rp * RST + cb2 + j * 8];
                uint2 hi = *(const uint2*)&smem[rp * RST + cb2 + j * 8 + 4];
                *(uint4*)&outp[(size_t)row * N + bn + cb2 + j * 8] =
                    make_uint4(lo.x, lo.y, hi.x, hi.y);
            }
        }
    } else {
#pragma unroll
        for (int mi = 0; mi < 8; ++mi)
#pragma unroll
            for (int nj = 0; nj < 4; ++nj) {
                int col = bn + wn + nj * 16 + l16;
                int h = col >> 6, d = col & 63;
                float bv_ = bias[col];
                int row0 = bm + wm + mi * 16 + quad * 4;
                int bb = row0 >> 11, l = row0 & 2047;
                // sigma: swap key-index bits 2<->3 (4-aligned blocks preserved)
                int lb = (l & ~12) | ((l & 4) << 1) | ((l & 8) >> 1);
                union { ushort4 u; bf16_t h4[4]; } pk;
#pragma unroll
                for (int r = 0; r < 4; ++r) pk.h4[r] = (bf16_t)(acc[mi][nj][r] + bv_);
                *(ushort4*)&vT[(((size_t)bb * 16 + h) * 64 + d) * 2048 + lb] = pk.u;
            }
    }
}

// ---------------------------------------------------------------------------
// Out-projection GEMM with FUSED softmax-normalize (absorbs old `combine`):
//   A = (Op0 + Op1) * (1/(lp0+lp1)) computed in registers during staging
//   (reg-staged A replicating gll16's exact LDS layout; W stays gll16).
//   dbuf + T2 swizzle. grid (64, 8). k0 window == one head block (h=k0>>6),
//   so the lp index is per-row uniform within a staging chunk.
// ---------------------------------------------------------------------------
__global__ __launch_bounds__(256) void out_gemm(const bf16_t* __restrict__ Op,
                                                const float* __restrict__ lpp,
                                                const bf16_t* __restrict__ W,
                                                const float* __restrict__ bias,
                                                float* __restrict__ out) {
    constexpr int Kdim = 1024, N = 1024;
    // buf b at smem + b*12288: A 4096 elems (64x64), B 8192 elems (128x64)
    __shared__ __attribute__((aligned(16))) bf16_t smem[2 * 12288];  // 48 KiB
    const int tid = threadIdx.x, wave = tid >> 6, lane = tid & 63;
    const int bm = blockIdx.x * 64, bn = blockIdx.y * 128;
    const int l16 = lane & 15, quad = lane >> 4;
    const int wm = (wave >> 1) * 32, wn = (wave & 1) * 64;
    const int grow = lane >> 3;
    const int gcol = (((lane & 7) ^ grow)) * 8;
    const int rsw = l16 & 7;
    f32x4 acc[2][4] = {};

    // per-lane A rows for the wave's two 8-row chunks
    const int arow0 = bm + (wave * 2 + 0) * 8 + grow;
    const int arow1 = bm + (wave * 2 + 1) * 8 + grow;

    uint4 a0p, a0q, a1p, a1q;   // Op0/Op1 16B chunks for the two rows
    float ivn0, ivn1;           // 1/(lp0+lp1) per row (h = k0>>6 uniform)

    auto loadA = [&](int k0) {
        const int h = k0 >> 6;
        a0p = *(const uint4*)(Op + (size_t)arow0 * Kdim + k0 + gcol);
        a0q = *(const uint4*)(Op + 4194304 + (size_t)arow0 * Kdim + k0 + gcol);
        a1p = *(const uint4*)(Op + (size_t)arow1 * Kdim + k0 + gcol);
        a1q = *(const uint4*)(Op + 4194304 + (size_t)arow1 * Kdim + k0 + gcol);
        const int li0 = ((arow0 >> 11) * 16 + h) * 2048 + (arow0 & 2047);
        const int li1 = ((arow1 >> 11) * 16 + h) * 2048 + (arow1 & 2047);
        ivn0 = 1.f / (lpp[li0] + lpp[65536 + li0]);
        ivn1 = 1.f / (lpp[li1] + lpp[65536 + li1]);
    };
    auto writeA = [&](bf16_t* As) {
        union { uint4 u; bf16_t h8[8]; } x, y, w0, w1;
        x.u = a0p; y.u = a0q;
#pragma unroll
        for (int i = 0; i < 8; ++i)
            w0.h8[i] = (bf16_t)(((float)x.h8[i] + (float)y.h8[i]) * ivn0);
        x.u = a1p; y.u = a1q;
#pragma unroll
        for (int i = 0; i < 8; ++i)
            w1.h8[i] = (bf16_t)(((float)x.h8[i] + (float)y.h8[i]) * ivn1);
        *(uint4*)&As[(wave * 2 + 0) * 512 + lane * 8] = w0.u;
        *(uint4*)&As[(wave * 2 + 1) * 512 + lane * 8] = w1.u;
    };
    auto stageW = [&](int k0, bf16_t* Bs) {
#pragma unroll
        for (int j = 0; j < 4; ++j) {
            int chunk = wave * 4 + j;
            int row = chunk * 8 + grow;
            gll16(W + (size_t)(bn + row) * Kdim + k0 + gcol, Bs + chunk * 512);
        }
    };
    auto compute = [&](const bf16_t* As, const bf16_t* Bs) {
#pragma unroll
        for (int ks = 0; ks < 64; ks += 32) {
            const int so0 = (((ks >> 3) + quad) ^ rsw) * 8;
            bf16x8 af[2], bf[4];
#pragma unroll
            for (int i = 0; i < 2; ++i)
                af[i] = *(const bf16x8*)&As[(wm + i * 16 + l16) * 64 + so0];
#pragma unroll
            for (int i = 0; i < 4; ++i)
                bf[i] = *(const bf16x8*)&Bs[(wn + i * 16 + l16) * 64 + so0];
#pragma unroll
            for (int i = 0; i < 2; ++i)
#pragma unroll
                for (int j = 0; j < 4; ++j)
                    acc[i][j] = MFMA16(af[i], bf[j], acc[i][j]);
        }
    };

    // prologue: tile 0 -> buf0
    loadA(0);
    stageW(0, smem + 4096);
    writeA(smem);            // compiler waits vmcnt for a-regs only
    __syncthreads();         // drains gll16 (vmcnt 0) + ds writes, barrier
    int cur = 0;
    for (int t = 0; t < 15; ++t) {
        bf16_t* nb = smem + (cur ^ 1) * 12288;
        loadA((t + 1) * 64);           // A regs for next tile (in flight)
        stageW((t + 1) * 64, nb + 4096);  // W gll16 for next tile (in flight)
        bf16_t* cb = smem + cur * 12288;
        compute(cb, cb + 4096);        // MFMA hides both
        writeA(nb);                    // waits only the a-regs, not gll16
        asm volatile("s_waitcnt vmcnt(0)" ::: "memory");
        __syncthreads();
        cur ^= 1;
    }
    {
        bf16_t* cb = smem + cur * 12288;
        compute(cb, cb + 4096);
    }

#pragma unroll
    for (int mi = 0; mi < 2; ++mi)
#pragma unroll
        for (int nj = 0; nj < 4; ++nj) {
            int col = bn + wn + nj * 16 + l16;
            float bv_ = bias[col];
#pragma unroll
            for (int r = 0; r < 4; ++r) {
                int row = bm + wm + mi * 16 + quad * 4 + r;
                out[(size_t)row * N + col] = acc[mi][nj][r] + bv_;
            }
        }
}

// ---------------------------------------------------------------------------
// Flash attention v8: 2 query sub-blocks per wave (LDS-frag reuse x2).
//  Each K/V fragment read from LDS feeds TWO MFMA32s: 32 MFMA per 16 frag
//  reads per tile — halves LDS bytes/MFMA.  512 blocks (2/CU) -> dbuf +
//  async-stage pipeline kept (TLP alone no longer hides HBM latency).
//  One lgkmcnt barrier per tile; vmcnt NOT drained in loop.
// Split-K(2), stride-68 LDS (conflict-free), no-max softmax, q pre-scaled
// by 0.125*log2(e) -> exp2. LDS 34.8 KB.
// ---------------------------------------------------------------------------
__global__ __launch_bounds__(256, 2) void attn8(const bf16_t* __restrict__ qo,
                                                const bf16_t* __restrict__ ko,
                                                const bf16_t* __restrict__ vT,
                                                bf16_t* __restrict__ Op,
                                                float* __restrict__ lpp) {
    constexpr int L = 2048, D = 1024, ST = 68;
    constexpr int BUF = 2 * 64 * ST;  // one (K,V) buffer pair: 8704 elems
    __shared__ __attribute__((aligned(16))) bf16_t smem[2 * BUF];  // 34.8 KB

    const int tid = threadIdx.x, wave = tid >> 6, lane = tid & 63;
    const int l31 = lane & 31, hi = lane >> 5;
    const int b = blockIdx.x >> 4, h = blockIdx.x & 15;
    const int q0 = blockIdx.y * 256;
    const int split = blockIdx.z;
    bf16_t* Opart = Op + (size_t)split * 4194304;
    float* lpart = lpp + split * 65536;

    // staging indices: thread -> (row 0..63, 16-elem column group 0..3)
    const int rloc = tid >> 2, cg = tid & 3;
    const bf16_t* kbase = ko + ((size_t)b * L + rloc) * D + h * 64 + cg * 16;
    const bf16_t* vbase = vT + (((size_t)b * 16 + h) * 64 + rloc) * L + cg * 16;

    // ---- Q fragments, two sub-blocks (B-operand layout: lane = query) ----
    bf16x8 qfa[4], qfb[4];
    {
        const bf16_t* qa = qo + ((size_t)b * L + q0 + wave * 32 + l31) * D + h * 64 + hi * 8;
        const bf16_t* qb2 = qa + (size_t)128 * D;
#pragma unroll
        for (int ks = 0; ks < 4; ++ks) {
            qfa[ks] = *(const bf16x8*)(qa + ks * 16);
            qfb[ks] = *(const bf16x8*)(qb2 + ks * 16);
        }
    }

    f32x16 o0a{}, o1a{}, o0b{}, o1b{};  // O^T: lane = query, reg/hi = d
    float lpla = 0.f, lplb = 0.f;       // per-lane (query) partial row sums

    const int kt0 = split * 16, kt1 = kt0 + 16;

    uint4 ka, kc, va, vc;  // staging regs (one tile in flight)
    auto gload = [&](int kt) {
        const size_t koff = (size_t)(kt * 64) * D;
        const int voff = kt * 64;
        ka = *(const uint4*)(kbase + koff);
        kc = *(const uint4*)(kbase + koff + 8);
        va = *(const uint4*)(vbase + voff);
        vc = *(const uint4*)(vbase + voff + 8);
    };
    auto swrite = [&](bf16_t* buf) {
        bf16_t* kd = &buf[rloc * ST + cg * 16];
        bf16_t* vd = &buf[64 * ST + rloc * ST + cg * 16];
        *(uint2*)(kd + 0)  = make_uint2(ka.x, ka.y);
        *(uint2*)(kd + 4)  = make_uint2(ka.z, ka.w);
        *(uint2*)(kd + 8)  = make_uint2(kc.x, kc.y);
        *(uint2*)(kd + 12) = make_uint2(kc.z, kc.w);
        *(uint2*)(vd + 0)  = make_uint2(va.x, va.y);
        *(uint2*)(vd + 4)  = make_uint2(va.z, va.w);
        *(uint2*)(vd + 8)  = make_uint2(vc.x, vc.y);
        *(uint2*)(vd + 12) = make_uint2(vc.z, vc.w);
    };

    // prologue: tile kt0 -> buf0; tile kt0+1 issued (arrives during iter 0)
    gload(kt0);
    swrite(smem);
    gload(kt0 + 1 < kt1 ? kt0 + 1 : kt1 - 1);
    asm volatile("s_waitcnt lgkmcnt(0)" ::: "memory");
    __builtin_amdgcn_s_barrier();

    int cur = 0;
    for (int kt = kt0; kt < kt1; ++kt) {
        // write the arrived next tile into the other buffer, issue kt+2;
        // both overlap this tile's MFMA/VALU below.
        swrite(smem + (cur ^ 1) * BUF);
        gload(kt + 2 < kt1 ? kt + 2 : kt1 - 1);  // clamped (redundant at tail)
        const bf16_t* ksm = smem + cur * BUF;
        const bf16_t* vsm = ksm + 64 * ST;

        // ---- S^T = K Q^T : each k frag feeds both q sub-blocks ----
        f32x16 s0a{}, s1a{}, s0b{}, s1b{};
        __builtin_amdgcn_s_setprio(1);
#pragma unroll
        for (int ks = 0; ks < 4; ++ks) {
            bf16x8 k0 = ld_frag68(&ksm[l31 * ST + ks * 16 + hi * 8]);
            bf16x8 k1 = ld_frag68(&ksm[(32 + l31) * ST + ks * 16 + hi * 8]);
            s0a = MFMA32(k0, qfa[ks], s0a);
            s1a = MFMA32(k1, qfa[ks], s1a);
            s0b = MFMA32(k0, qfb[ks], s0b);
            s1b = MFMA32(k1, qfb[ks], s1b);
        }
        __builtin_amdgcn_s_setprio(0);

        // ---- p = exp2(s) -> P^T B-frags; O^T += V^T P^T (v frags x2) ----
#pragma unroll
        for (int t = 0; t < 4; ++t) {
            union { bf16x8 v; bf16_t e[8]; } pfa, pfb;
#pragma unroll
            for (int j = 0; j < 8; ++j) {
                float sva = (t < 2) ? s0a[(t & 1) * 8 + j] : s1a[(t & 1) * 8 + j];
                float svb = (t < 2) ? s0b[(t & 1) * 8 + j] : s1b[(t & 1) * 8 + j];
                float pa = __builtin_amdgcn_exp2f(sva);
                float pb = __builtin_amdgcn_exp2f(svb);
                lpla += pa; lplb += pb;
                pfa.e[j] = (bf16_t)pa;
                pfb.e[j] = (bf16_t)pb;
            }
            bf16x8 v0 = ld_frag68(&vsm[l31 * ST + t * 16 + hi * 8]);
            bf16x8 v1 = ld_frag68(&vsm[(32 + l31) * ST + t * 16 + hi * 8]);
            __builtin_amdgcn_s_setprio(1);
            o0a = MFMA32(v0, pfa.v, o0a);
            o1a = MFMA32(v1, pfa.v, o1a);
            o0b = MFMA32(v0, pfb.v, o0b);
            o1b = MFMA32(v1, pfb.v, o1b);
            __builtin_amdgcn_s_setprio(0);
        }

        // drain ds ops only (NOT vmcnt: kt+2 loads stay in flight)
        asm volatile("s_waitcnt lgkmcnt(0)" ::: "memory");
        __builtin_amdgcn_s_barrier();
        cur ^= 1;
    }

    // ---- complete per-query row sums (hi halves hold disjoint keys) ----
    lpla += __shfl_xor(lpla, 32, 64);
    lplb += __shfl_xor(lplb, 32, 64);
    if (hi == 0) {
        lpart[((size_t)b * 16 + h) * 2048 + q0 + wave * 32 + l31] = lpla;
        lpart[((size_t)b * 16 + h) * 2048 + q0 + 128 + wave * 32 + l31] = lplb;
    }

    // ---- transpose O^T -> row-major via wave-private LDS, store x2 ----
    __syncthreads();  // all waves done with K/V buffers
    bf16_t* ew = smem + wave * (32 * ST);
#pragma unroll
    for (int r = 0; r < 16; r += 2) {
        int d = (r & 3) + 8 * (r >> 2) + 4 * hi;
        *(bf16x2*)&ew[l31 * ST + d] = bf16x2{(bf16_t)o0a[r], (bf16_t)o0a[r + 1]};
        *(bf16x2*)&ew[l31 * ST + 32 + d] = bf16x2{(bf16_t)o1a[r], (bf16_t)o1a[r + 1]};
    }
    // wave-private region: compiler's lgkmcnt ordering covers RAW/WAR
#pragma unroll
    for (int p = 0; p < 4; ++p) {
        int rr = p * 8 + (lane >> 3);
        int cc = (lane & 7) * 8;
        uint2 lo = *(const uint2*)&ew[rr * ST + cc];
        uint2 hi2 = *(const uint2*)&ew[rr * ST + cc + 4];
        *(uint4*)&Opart[((size_t)b * L + q0 + wave * 32 + rr) * D + h * 64 + cc] =
            make_uint4(lo.x, lo.y, hi2.x, hi2.y);
    }
#pragma unroll
    for (int r = 0; r < 16; r += 2) {
        int d = (r & 3) + 8 * (r >> 2) + 4 * hi;
        *(bf16x2*)&ew[l31 * ST + d] = bf16x2{(bf16_t)o0b[r], (bf16_t)o0b[r + 1]};
        *(bf16x2*)&ew[l31 * ST + 32 + d] = bf16x2{(bf16_t)o1b[r], (bf16_t)o1b[r + 1]};
    }
#pragma unroll
    for (int p = 0; p < 4; ++p) {
        int rr = p * 8 + (lane >> 3);
        int cc = (lane & 7) * 8;
        uint2 lo = *(const uint2*)&ew[rr * ST + cc];
        uint2 hi2 = *(const uint2*)&ew[rr * ST + cc + 4];
        *(uint4*)&Opart[((size_t)b * L + q0 + 128 + wave * 32 + rr) * D + h * 64 + cc] =
            make_uint4(lo.x, lo.y, hi2.x, hi2.y);
    }
}

// ---------------------------------------------------------------------------
extern "C" void kernel_launch(void* const* d_in, const int* in_sizes, int n_in,
                              void* d_out, int out_size, void* d_ws, size_t ws_size,
                              hipStream_t stream) {
    const float* Q  = (const float*)d_in[0];
    const float* Kx = (const float*)d_in[1];
    const float* V  = (const float*)d_in[2];
    const float* Wq = (const float*)d_in[3];
    const float* bq = (const float*)d_in[4];
    const float* Wk = (const float*)d_in[5];
    const float* bk = (const float*)d_in[6];
    const float* Wv = (const float*)d_in[7];
    const float* bv = (const float*)d_in[8];
    const float* Wo = (const float*)d_in[9];
    const float* bo = (const float*)d_in[10];

    // ws (bf16 elems), 40 MiB total:
    //  [0,4M)      Qb   -> after qkv: Op0
    //  [4M,8M)     Kb   -> after qkv: Op1
    //  [8M,12M)    Vb   (dead after qkv)
    //  [12M,~12.8M) Wqb -> after qkv: lp partials (131072 fp32)
    //  [13M,14M)   Wkb   [13631488]
    //  [14M,15M)   Wvb   [14680064]
    //  [15M,16M)   Wob   [15728640] (live until out_gemm)
    //  [16M,20M)   vT    [16777216]
    bf16_t* ws0 = (bf16_t*)d_ws;
    bf16_t* Qb  = ws0;
    bf16_t* Kb  = ws0 + 4194304;
    bf16_t* Vb  = ws0 + 8388608;
    bf16_t* Wqb = ws0 + 12582912;
    bf16_t* Wkb = ws0 + 13631488;
    bf16_t* Wvb = ws0 + 14680064;
    bf16_t* Wob = ws0 + 15728640;
    bf16_t* vT  = ws0 + 16777216;
    bf16_t* Op  = Qb;                   // 2 x 4M bf16 partials
    float*  lpp = (float*)Wqb;          // 2 x 65536 fp32
    bf16_t* qo = (bf16_t*)d_out;        // parked in d_out, dead before out_gemm
    bf16_t* ko = qo + 4194304;

    convert_all<<<8192, 256, 0, stream>>>(Q, Kx, V, Wq, Wk, Wv, Wo, ws0);
    qkv_gemm<<<dim3(16, 4, 3), 512, 0, stream>>>(Qb, Kb, Vb, Wqb, Wkb, Wvb,
                                                 bq, bk, bv, qo, ko, vT);
    attn8<<<dim3(32, 8, 2), 256, 0, stream>>>(qo, ko, vT, Op, lpp);
    out_gemm<<<dim3(64, 8), 256, 0, stream>>>(Op, lpp, Wob, bo, (float*)d_out);
}